// Round 1
// baseline (3361.574 us; speedup 1.0000x reference)
//
#include <hip/hip_runtime.h>
#include <hip/hip_bf16.h>
#include <math.h>

#define N_NODES 50000

// ---------------- degree / norm ----------------

__global__ void deg_kernel(const int* __restrict__ dst, float* __restrict__ deg, int E) {
    int e = blockIdx.x * blockDim.x + threadIdx.x;
    if (e < E) atomicAdd(&deg[dst[e]], 1.0f);
}

__global__ void inv_sqrt_kernel(float* __restrict__ deg, int n) {
    int i = blockIdx.x * blockDim.x + threadIdx.x;
    if (i < n) deg[i] = rsqrtf(fmaxf(deg[i], 1.0f));
}

__global__ void norm_kernel(const int* __restrict__ src, const int* __restrict__ dst,
                            const float* __restrict__ inv, float* __restrict__ norm, int E) {
    int e = blockIdx.x * blockDim.x + threadIdx.x;
    if (e < E) norm[e] = inv[src[e]] * inv[dst[e]];
}

// ---------------- scatter-add aggregation ----------------
// F floats per edge; LPE = F/4 lanes per edge, each lane handles a float4.

template<int F>
__global__ void scatter_add_kernel(const float* __restrict__ x, const int* __restrict__ src,
                                   const int* __restrict__ dst, const float* __restrict__ nrm,
                                   float* __restrict__ agg, int E) {
    constexpr int LPE = F / 4;
    long long gid = (long long)blockIdx.x * blockDim.x + threadIdx.x;
    int e = (int)(gid / LPE);
    int l = (int)(gid % LPE);
    if (e >= E) return;
    int s = src[e];
    int d = dst[e];
    float n = nrm[e];
    float4 v = ((const float4*)(x + (size_t)s * F))[l];
    float* o = agg + (size_t)d * F + (size_t)l * 4;
    atomicAdd(o + 0, v.x * n);
    atomicAdd(o + 1, v.y * n);
    atomicAdd(o + 2, v.z * n);
    atomicAdd(o + 3, v.w * n);
}

// ---------------- GEMM + bias + ReLU ----------------
// A: [M,K] row-major, W: [K,256] row-major, out: [M,256]. 16 rows per block,
// 256 threads = one output column each, A-rows staged in LDS.

template<int K>
__global__ void gemm_bias_relu_kernel(const float* __restrict__ A, const float* __restrict__ W,
                                      const float* __restrict__ b, float* __restrict__ out) {
    __shared__ float xs[16 * K];
    int row0 = blockIdx.x * 16;
    int tid = threadIdx.x;

    const float4* Ag = (const float4*)(A + (size_t)row0 * K);
    float4* xs4 = (float4*)xs;
    #pragma unroll
    for (int i = tid; i < 16 * K / 4; i += 256) xs4[i] = Ag[i];
    __syncthreads();

    float acc[16];
    #pragma unroll
    for (int r = 0; r < 16; ++r) acc[r] = 0.0f;

    for (int k = 0; k < K; ++k) {
        float w = W[(size_t)k * 256 + tid];
        #pragma unroll
        for (int r = 0; r < 16; ++r) acc[r] = fmaf(xs[r * K + k], w, acc[r]);
    }

    float bias = b[tid];
    #pragma unroll
    for (int r = 0; r < 16; ++r) {
        float v = acc[r] + bias;
        out[(size_t)(row0 + r) * 256 + tid] = v > 0.0f ? v : 0.0f;
    }
}

// ---------------- dense head + softmax ----------------
// one wave (64 threads) per row; C=40 classes, K=256.

__global__ void dense_softmax_kernel(const float* __restrict__ h, const float* __restrict__ Wd,
                                     const float* __restrict__ bd, float* __restrict__ out) {
    int row = blockIdx.x;
    int lane = threadIdx.x; // 0..63
    __shared__ float hs[256];
    ((float4*)hs)[lane] = ((const float4*)(h + (size_t)row * 256))[lane];
    __syncthreads();

    float logit = -INFINITY;
    if (lane < 40) {
        float acc = bd[lane];
        #pragma unroll 8
        for (int k = 0; k < 256; ++k) acc = fmaf(hs[k], Wd[(size_t)k * 40 + lane], acc);
        logit = acc;
    }
    float m = logit;
    #pragma unroll
    for (int off = 32; off > 0; off >>= 1) m = fmaxf(m, __shfl_xor(m, off));
    float e = (lane < 40) ? expf(logit - m) : 0.0f;
    float s = e;
    #pragma unroll
    for (int off = 32; off > 0; off >>= 1) s += __shfl_xor(s, off);
    if (lane < 40) out[(size_t)row * 40 + lane] = e / s;
}

// ---------------- launch ----------------

extern "C" void kernel_launch(void* const* d_in, const int* in_sizes, int n_in,
                              void* d_out, int out_size, void* d_ws, size_t ws_size,
                              hipStream_t stream) {
    const float* x  = (const float*)d_in[0];
    const int*   ei = (const int*)d_in[1];
    const float* W1 = (const float*)d_in[2];
    const float* b1 = (const float*)d_in[3];
    const float* W2 = (const float*)d_in[4];
    const float* b2 = (const float*)d_in[5];
    const float* Wd = (const float*)d_in[6];
    const float* bd = (const float*)d_in[7];
    float* out = (float*)d_out;

    const int N = N_NODES;
    const int E = in_sizes[1] / 2;
    const int* src = ei;
    const int* dst = ei + E;

    // workspace layout (bytes, 1KB-aligned)
    char* ws = (char*)d_ws;
    size_t off = 0;
    auto alloc = [&](size_t bytes) { char* p = ws + off; off += (bytes + 1023) & ~(size_t)1023; return p; };
    float* deg  = (float*)alloc((size_t)N * 4);            // then becomes inv_sqrt
    float* nrm  = (float*)alloc((size_t)E * 4);
    float* agg1 = (float*)alloc((size_t)N * 128 * 4);
    float* h1   = (float*)alloc((size_t)N * 256 * 4);      // reused for h2
    float* agg2 = (float*)alloc((size_t)N * 256 * 4);
    float* h2 = h1;

    // zero the accumulators
    hipMemsetAsync(deg,  0, (size_t)N * 4, stream);
    hipMemsetAsync(agg1, 0, (size_t)N * 128 * 4, stream);
    hipMemsetAsync(agg2, 0, (size_t)N * 256 * 4, stream);

    // degree + norm
    deg_kernel<<<(E + 255) / 256, 256, 0, stream>>>(dst, deg, E);
    inv_sqrt_kernel<<<(N + 255) / 256, 256, 0, stream>>>(deg, N);
    norm_kernel<<<(E + 255) / 256, 256, 0, stream>>>(src, dst, deg, nrm, E);

    // conv1: scatter x*norm into agg1 [N,128], then h1 = relu(agg1@W1 + b1)
    {
        long long total = (long long)E * (128 / 4);
        int blocks = (int)((total + 255) / 256);
        scatter_add_kernel<128><<<blocks, 256, 0, stream>>>(x, src, dst, nrm, agg1, E);
    }
    gemm_bias_relu_kernel<128><<<N / 16, 256, 0, stream>>>(agg1, W1, b1, h1);

    // conv2: scatter h1*norm into agg2 [N,256], then h2 = relu(agg2@W2 + b2)
    {
        long long total = (long long)E * (256 / 4);
        int blocks = (int)((total + 255) / 256);
        scatter_add_kernel<256><<<blocks, 256, 0, stream>>>(h1, src, dst, nrm, agg2, E);
    }
    gemm_bias_relu_kernel<256><<<N / 16, 256, 0, stream>>>(agg2, W2, b2, h2);

    // dense + softmax
    dense_softmax_kernel<<<N, 64, 0, stream>>>(h2, Wd, bd, out);
}

// Round 2
// 608.091 us; speedup vs baseline: 5.5281x; 5.5281x over previous
//
#include <hip/hip_runtime.h>
#include <hip/hip_bf16.h>
#include <math.h>

#define N_NODES 50000

// ---------------- degree (int histogram) ----------------

__global__ void deg_kernel(const int* __restrict__ dst, int* __restrict__ deg, int E) {
    int e = blockIdx.x * blockDim.x + threadIdx.x;
    if (e < E) atomicAdd(&deg[dst[e]], 1);
}

__global__ void inv_sqrt_kernel(const int* __restrict__ deg, float* __restrict__ inv, int n) {
    int i = blockIdx.x * blockDim.x + threadIdx.x;
    if (i < n) inv[i] = rsqrtf(fmaxf((float)deg[i], 1.0f));
}

// ---------------- exclusive prefix scan (single block, 1024 threads) ----------------

__global__ void scan_kernel(const int* __restrict__ deg, int* __restrict__ rowptr, int n) {
    __shared__ int part[1024];
    int tid = threadIdx.x;
    int per = (n + 1023) >> 10;
    int base = tid * per;
    int sum = 0;
    for (int i = 0; i < per; ++i) {
        int idx = base + i;
        if (idx < n) sum += deg[idx];
    }
    part[tid] = sum;
    __syncthreads();
    // Hillis-Steele inclusive scan
    for (int off = 1; off < 1024; off <<= 1) {
        int v = (tid >= off) ? part[tid - off] : 0;
        __syncthreads();
        part[tid] += v;
        __syncthreads();
    }
    int run = part[tid] - sum;  // exclusive prefix of this chunk
    for (int i = 0; i < per; ++i) {
        int idx = base + i;
        if (idx < n) { rowptr[idx] = run; run += deg[idx]; }
    }
    if (tid == 1023) rowptr[n] = part[1023];
}

__global__ void copy_int_kernel(const int* __restrict__ a, int* __restrict__ b, int n) {
    int i = blockIdx.x * blockDim.x + threadIdx.x;
    if (i < n) b[i] = a[i];
}

// ---------------- bucket edges by dst (counting sort fill) ----------------

__global__ void fill_kernel(const int* __restrict__ src, const int* __restrict__ dst,
                            const float* __restrict__ inv, int* __restrict__ cursor,
                            int* __restrict__ src_s, float* __restrict__ norm_s, int E) {
    int e = blockIdx.x * blockDim.x + threadIdx.x;
    if (e >= E) return;
    int s = src[e];
    int d = dst[e];
    int pos = atomicAdd(&cursor[d], 1);
    src_s[pos] = s;
    norm_s[pos] = inv[s] * inv[d];
}

// ---------------- gather aggregation: one wave per node ----------------

template<int F>
__global__ void gather_agg_kernel(const float* __restrict__ x, const int* __restrict__ rowptr,
                                  const int* __restrict__ src_s, const float* __restrict__ norm_s,
                                  float* __restrict__ agg) {
    int node = blockIdx.x * 4 + (threadIdx.x >> 6);
    if (node >= N_NODES) return;
    int lane = threadIdx.x & 63;
    int beg = rowptr[node];
    int end = rowptr[node + 1];

    if constexpr (F == 128) {
        float2 acc = {0.0f, 0.0f};
        for (int p = beg; p < end; ++p) {
            int s = src_s[p];
            float nv = norm_s[p];
            float2 v = ((const float2*)(x + (size_t)s * F))[lane];
            acc.x = fmaf(v.x, nv, acc.x);
            acc.y = fmaf(v.y, nv, acc.y);
        }
        ((float2*)(agg + (size_t)node * F))[lane] = acc;
    } else {
        float4 acc = {0.0f, 0.0f, 0.0f, 0.0f};
        for (int p = beg; p < end; ++p) {
            int s = src_s[p];
            float nv = norm_s[p];
            float4 v = ((const float4*)(x + (size_t)s * F))[lane];
            acc.x = fmaf(v.x, nv, acc.x);
            acc.y = fmaf(v.y, nv, acc.y);
            acc.z = fmaf(v.z, nv, acc.z);
            acc.w = fmaf(v.w, nv, acc.w);
        }
        ((float4*)(agg + (size_t)node * F))[lane] = acc;
    }
}

// ---------------- GEMM + bias + ReLU ----------------
// A: [M,K] row-major, W: [K,256] row-major, out: [M,256]. 16 rows per block,
// 256 threads = one output column each, A-rows staged in LDS.

template<int K>
__global__ void gemm_bias_relu_kernel(const float* __restrict__ A, const float* __restrict__ W,
                                      const float* __restrict__ b, float* __restrict__ out) {
    __shared__ float xs[16 * K];
    int row0 = blockIdx.x * 16;
    int tid = threadIdx.x;

    const float4* Ag = (const float4*)(A + (size_t)row0 * K);
    float4* xs4 = (float4*)xs;
    #pragma unroll
    for (int i = tid; i < 16 * K / 4; i += 256) xs4[i] = Ag[i];
    __syncthreads();

    float acc[16];
    #pragma unroll
    for (int r = 0; r < 16; ++r) acc[r] = 0.0f;

    for (int k = 0; k < K; ++k) {
        float w = W[(size_t)k * 256 + tid];
        #pragma unroll
        for (int r = 0; r < 16; ++r) acc[r] = fmaf(xs[r * K + k], w, acc[r]);
    }

    float bias = b[tid];
    #pragma unroll
    for (int r = 0; r < 16; ++r) {
        float v = acc[r] + bias;
        out[(size_t)(row0 + r) * 256 + tid] = v > 0.0f ? v : 0.0f;
    }
}

// ---------------- dense head + softmax ----------------
// one wave (64 threads) per row; C=40 classes, K=256.

__global__ void dense_softmax_kernel(const float* __restrict__ h, const float* __restrict__ Wd,
                                     const float* __restrict__ bd, float* __restrict__ out) {
    int row = blockIdx.x;
    int lane = threadIdx.x; // 0..63
    __shared__ float hs[256];
    ((float4*)hs)[lane] = ((const float4*)(h + (size_t)row * 256))[lane];
    __syncthreads();

    float logit = -INFINITY;
    if (lane < 40) {
        float acc = bd[lane];
        #pragma unroll 8
        for (int k = 0; k < 256; ++k) acc = fmaf(hs[k], Wd[(size_t)k * 40 + lane], acc);
        logit = acc;
    }
    float m = logit;
    #pragma unroll
    for (int off = 32; off > 0; off >>= 1) m = fmaxf(m, __shfl_xor(m, off));
    float e = (lane < 40) ? expf(logit - m) : 0.0f;
    float s = e;
    #pragma unroll
    for (int off = 32; off > 0; off >>= 1) s += __shfl_xor(s, off);
    if (lane < 40) out[(size_t)row * 40 + lane] = e / s;
}

// ---------------- launch ----------------

extern "C" void kernel_launch(void* const* d_in, const int* in_sizes, int n_in,
                              void* d_out, int out_size, void* d_ws, size_t ws_size,
                              hipStream_t stream) {
    const float* x  = (const float*)d_in[0];
    const int*   ei = (const int*)d_in[1];
    const float* W1 = (const float*)d_in[2];
    const float* b1 = (const float*)d_in[3];
    const float* W2 = (const float*)d_in[4];
    const float* b2 = (const float*)d_in[5];
    const float* Wd = (const float*)d_in[6];
    const float* bd = (const float*)d_in[7];
    float* out = (float*)d_out;

    const int N = N_NODES;
    const int E = in_sizes[1] / 2;
    const int* src = ei;
    const int* dst = ei + E;

    // workspace layout (bytes, 1KB-aligned). Total ~108 MB.
    char* ws = (char*)d_ws;
    size_t off = 0;
    auto alloc = [&](size_t bytes) { char* p = ws + off; off += (bytes + 1023) & ~(size_t)1023; return p; };
    int*   deg    = (int*)alloc((size_t)N * 4);
    float* inv    = (float*)alloc((size_t)N * 4);
    int*   rowptr = (int*)alloc((size_t)(N + 1) * 4);
    int*   cursor = (int*)alloc((size_t)N * 4);
    int*   src_s  = (int*)alloc((size_t)E * 4);
    float* norm_s = (float*)alloc((size_t)E * 4);
    float* h1     = (float*)alloc((size_t)N * 256 * 4);
    float* agg2   = (float*)alloc((size_t)N * 256 * 4);
    float* agg1   = agg2;   // agg1 [N,128] aliases agg2 region (lifetimes disjoint)
    float* h2     = h1;     // h2 reuses h1

    hipMemsetAsync(deg, 0, (size_t)N * 4, stream);

    // degree -> inv_sqrt -> rowptr -> cursor -> bucketed (src_s, norm_s)
    deg_kernel<<<(E + 255) / 256, 256, 0, stream>>>(dst, deg, E);
    inv_sqrt_kernel<<<(N + 255) / 256, 256, 0, stream>>>(deg, inv, N);
    scan_kernel<<<1, 1024, 0, stream>>>(deg, rowptr, N);
    copy_int_kernel<<<(N + 255) / 256, 256, 0, stream>>>(rowptr, cursor, N);
    fill_kernel<<<(E + 255) / 256, 256, 0, stream>>>(src, dst, inv, cursor, src_s, norm_s, E);

    // conv1: gather-aggregate into agg1 [N,128], then h1 = relu(agg1@W1 + b1)
    gather_agg_kernel<128><<<(N + 3) / 4, 256, 0, stream>>>(x, rowptr, src_s, norm_s, agg1);
    gemm_bias_relu_kernel<128><<<N / 16, 256, 0, stream>>>(agg1, W1, b1, h1);

    // conv2: gather-aggregate h1 into agg2 [N,256], then h2 = relu(agg2@W2 + b2)
    gather_agg_kernel<256><<<(N + 3) / 4, 256, 0, stream>>>(h1, rowptr, src_s, norm_s, agg2);
    gemm_bias_relu_kernel<256><<<N / 16, 256, 0, stream>>>(agg2, W2, b2, h2);

    // dense + softmax
    dense_softmax_kernel<<<N, 64, 0, stream>>>(h2, Wd, bd, out);
}